// Round 1
// baseline (8979.021 us; speedup 1.0000x reference)
//
#include <hip/hip_runtime.h>

#define P_   128
#define H_   512
#define QE_  100000
#define Q_   300000
#define NIMG 1000
#define NNZ_ 8000000
#define NC_  1172   // ceil(Q_/256)

#define GTM 64
#define GTN 64
#define GTK 16
#define LDP 68      // padded LDS row (floats); 68*4B = 272B, multiple of 16B

// ---------------- forward FC: out = tanh(A[M,K] @ W[K,512] + b) ----------------
__global__ __launch_bounds__(256) void k_fc_fwd(
    const float* __restrict__ A, const float* __restrict__ W,
    const float* __restrict__ bias, float* __restrict__ out,
    int M, int K) {
  __shared__ __align__(16) float As[GTK][LDP];
  __shared__ __align__(16) float Ws[GTK][LDP];
  const int tid = threadIdx.x;
  const int tx = tid & 15, ty = tid >> 4;
  const int bm = blockIdx.x * GTM, bn = blockIdx.y * GTN;
  float acc[4][4] = {};
  for (int kt = 0; kt < K; kt += GTK) {
#pragma unroll
    for (int i = 0; i < 4; i++) {          // A tile: coalesced read, transposed store
      int li = tid + i * 256;
      int m = li >> 4, kk = li & 15;
      int gm = bm + m;
      As[kk][m] = (gm < M) ? A[(size_t)gm * K + kt + kk] : 0.f;
    }
#pragma unroll
    for (int i = 0; i < 4; i++) {          // W tile: [k][n], coalesced over n
      int li = tid + i * 256;
      int kk = li >> 6, n = li & 63;
      Ws[kk][n] = W[(size_t)(kt + kk) * H_ + bn + n];
    }
    __syncthreads();
#pragma unroll
    for (int kk = 0; kk < GTK; kk++) {
      const float4 av = *(const float4*)&As[kk][ty * 4];
      const float4 bv = *(const float4*)&Ws[kk][tx * 4];
      float a[4] = {av.x, av.y, av.z, av.w};
      float b[4] = {bv.x, bv.y, bv.z, bv.w};
#pragma unroll
      for (int i = 0; i < 4; i++)
#pragma unroll
        for (int j = 0; j < 4; j++) acc[i][j] = fmaf(a[i], b[j], acc[i][j]);
    }
    __syncthreads();
  }
#pragma unroll
  for (int i = 0; i < 4; i++) {
    int gm = bm + ty * 4 + i;
    if (gm < M) {
#pragma unroll
      for (int j = 0; j < 4; j++) {
        int gn = bn + tx * 4 + j;
        out[(size_t)gm * H_ + gn] = tanhf(acc[i][j] + bias[gn]);
      }
    }
  }
}

// ------- bwd1: da0 = (B @ w1^T) .* (1-h0^2), where B[m,k] = w2[k]*(1-h1[m,k]^2) -------
__global__ __launch_bounds__(256) void k_bwd1(
    const float* __restrict__ h1, const float* __restrict__ w2,
    const float* __restrict__ w1, const float* __restrict__ h0,
    float* __restrict__ da0, int M) {
  __shared__ __align__(16) float As[GTK][LDP];
  __shared__ __align__(16) float Ws[GTK][LDP];
  const int tid = threadIdx.x;
  const int tx = tid & 15, ty = tid >> 4;
  const int bm = blockIdx.x * GTM, bn = blockIdx.y * GTN;
  float acc[4][4] = {};
  for (int kt = 0; kt < H_; kt += GTK) {
#pragma unroll
    for (int i = 0; i < 4; i++) {
      int li = tid + i * 256;
      int m = li >> 4, kk = li & 15;
      int gm = bm + m;
      float h = (gm < M) ? h1[(size_t)gm * H_ + kt + kk] : 0.f;
      As[kk][m] = w2[kt + kk] * (1.f - h * h);
    }
#pragma unroll
    for (int i = 0; i < 4; i++) {          // transposed B: Ws[k][n] = w1[n][k]
      int li = tid + i * 256;
      int n = li >> 4, kk = li & 15;
      Ws[kk][n] = w1[(size_t)(bn + n) * H_ + kt + kk];
    }
    __syncthreads();
#pragma unroll
    for (int kk = 0; kk < GTK; kk++) {
      const float4 av = *(const float4*)&As[kk][ty * 4];
      const float4 bv = *(const float4*)&Ws[kk][tx * 4];
      float a[4] = {av.x, av.y, av.z, av.w};
      float b[4] = {bv.x, bv.y, bv.z, bv.w};
#pragma unroll
      for (int i = 0; i < 4; i++)
#pragma unroll
        for (int j = 0; j < 4; j++) acc[i][j] = fmaf(a[i], b[j], acc[i][j]);
    }
    __syncthreads();
  }
#pragma unroll
  for (int i = 0; i < 4; i++) {
    int gm = bm + ty * 4 + i;
    if (gm < M) {
#pragma unroll
      for (int j = 0; j < 4; j++) {
        int gn = bn + tx * 4 + j;
        float h = h0[(size_t)gm * H_ + gn];
        da0[(size_t)gm * H_ + gn] = acc[i][j] * (1.f - h * h);
      }
    }
  }
}

// ------- bwd2: g = da0[M,512] @ w0^T -> dE rows [rowOff, rowOff+M), width 128 -------
__global__ __launch_bounds__(256) void k_bwd2(
    const float* __restrict__ da0, const float* __restrict__ w0,
    float* __restrict__ dE, int rowOff, int M) {
  __shared__ __align__(16) float As[GTK][LDP];
  __shared__ __align__(16) float Ws[GTK][LDP];
  const int tid = threadIdx.x;
  const int tx = tid & 15, ty = tid >> 4;
  const int bm = blockIdx.x * GTM, bn = blockIdx.y * GTN;
  float acc[4][4] = {};
  for (int kt = 0; kt < H_; kt += GTK) {
#pragma unroll
    for (int i = 0; i < 4; i++) {
      int li = tid + i * 256;
      int m = li >> 4, kk = li & 15;
      int gm = bm + m;
      As[kk][m] = (gm < M) ? da0[(size_t)gm * H_ + kt + kk] : 0.f;
    }
#pragma unroll
    for (int i = 0; i < 4; i++) {          // Ws[k][n] = w0[n][k] (w0 is [128,512])
      int li = tid + i * 256;
      int n = li >> 4, kk = li & 15;
      Ws[kk][n] = w0[(size_t)(bn + n) * H_ + kt + kk];
    }
    __syncthreads();
#pragma unroll
    for (int kk = 0; kk < GTK; kk++) {
      const float4 av = *(const float4*)&As[kk][ty * 4];
      const float4 bv = *(const float4*)&Ws[kk][tx * 4];
      float a[4] = {av.x, av.y, av.z, av.w};
      float b[4] = {bv.x, bv.y, bv.z, bv.w};
#pragma unroll
      for (int i = 0; i < 4; i++)
#pragma unroll
        for (int j = 0; j < 4; j++) acc[i][j] = fmaf(a[i], b[j], acc[i][j]);
    }
    __syncthreads();
  }
#pragma unroll
  for (int i = 0; i < 4; i++) {
    int gm = bm + ty * 4 + i;
    if (gm < M) {
#pragma unroll
      for (int j = 0; j < 4; j++) {
        int gn = bn + tx * 4 + j;
        dE[(size_t)(rowOff + gm) * P_ + gn] = acc[i][j];
      }
    }
  }
}

// ------- per-atom output energy: e = h1 . w2 + b2, atomicAdd into energy[idx] -------
__global__ __launch_bounds__(256) void k_out(
    const float* __restrict__ h1, const float* __restrict__ w2,
    const float* __restrict__ b2, const int* __restrict__ idx,
    float* __restrict__ energy, int M) {
  int w = threadIdx.x >> 6, lane = threadIdx.x & 63;
  int a = blockIdx.x * 4 + w;
  if (a >= M) return;
  float v = 0.f;
#pragma unroll
  for (int i = 0; i < 8; i++) {
    int j = lane + i * 64;
    v += h1[(size_t)a * H_ + j] * w2[j];
  }
#pragma unroll
  for (int off = 32; off; off >>= 1) v += __shfl_xor(v, off, 64);
  if (lane == 0) atomicAdd(&energy[idx[a]], v + b2[0]);
}

// ---------------- stable counting sort of 300k keys in [0,1000) ----------------
__device__ __forceinline__ int atom_key(int gi, const int* i0, const int* i1, const int* i2) {
  return gi < QE_ ? i0[gi] : (gi < 2 * QE_ ? i1[gi - QE_] : i2[gi - 2 * QE_]);
}

__global__ __launch_bounds__(256) void k_hist(
    const int* __restrict__ i0, const int* __restrict__ i1, const int* __restrict__ i2,
    int* __restrict__ chunkHist) {
  __shared__ int h[NIMG];
  for (int i = threadIdx.x; i < NIMG; i += 256) h[i] = 0;
  __syncthreads();
  int gi = blockIdx.x * 256 + threadIdx.x;
  if (gi < Q_) atomicAdd(&h[atom_key(gi, i0, i1, i2)], 1);
  __syncthreads();
  for (int i = threadIdx.x; i < NIMG; i += 256)
    chunkHist[(size_t)blockIdx.x * NIMG + i] = h[i];
}

// per-bin exclusive scan over chunks; chunkHist[c][b] <- sum of hist[c'<c][b]
__global__ __launch_bounds__(256) void k_scanchunks(int* __restrict__ chunkHist,
                                                   int* __restrict__ binTotals) {
  __shared__ int s[256];
  __shared__ int carry;
  const int b = blockIdx.x;
  if (threadIdx.x == 0) carry = 0;
  __syncthreads();
  for (int c0 = 0; c0 < NC_; c0 += 256) {
    int c = c0 + threadIdx.x;
    int v = (c < NC_) ? chunkHist[(size_t)c * NIMG + b] : 0;
    s[threadIdx.x] = v;
    __syncthreads();
#pragma unroll
    for (int off = 1; off < 256; off <<= 1) {
      int t = (threadIdx.x >= off) ? s[threadIdx.x - off] : 0;
      __syncthreads();
      s[threadIdx.x] += t;
      __syncthreads();
    }
    int incl = s[threadIdx.x];
    int base = carry;
    __syncthreads();
    if (c < NC_) chunkHist[(size_t)c * NIMG + b] = base + incl - v;
    if (threadIdx.x == 255) carry = base + s[255];
    __syncthreads();
  }
  if (threadIdx.x == 0) binTotals[b] = carry;
}

__global__ void k_binoffsets(const int* __restrict__ binTotals, int* __restrict__ binOffset) {
  if (threadIdx.x == 0 && blockIdx.x == 0) {
    int acc = 0;
    for (int b = 0; b < NIMG; b++) { binOffset[b] = acc; acc += binTotals[b]; }
  }
}

__global__ __launch_bounds__(256) void k_scatter(
    const int* __restrict__ i0, const int* __restrict__ i1, const int* __restrict__ i2,
    const int* __restrict__ chunkHist, const int* __restrict__ binOffset,
    int* __restrict__ ordered) {
  __shared__ int keys[256];
  int gi = blockIdx.x * 256 + threadIdx.x;
  int key = (gi < Q_) ? atom_key(gi, i0, i1, i2) : -1;
  keys[threadIdx.x] = key;
  __syncthreads();
  if (gi < Q_) {
    int rank = 0;
    for (int j = 0; j < threadIdx.x; j++) rank += (keys[j] == key) ? 1 : 0;
    ordered[binOffset[key] + chunkHist[(size_t)blockIdx.x * NIMG + key] + rank] = gi;
  }
}

// ---------------- force: 8M gathers + scatter-adds ----------------
__global__ __launch_bounds__(256) void k_force(
    const int* __restrict__ fp_rows, const int* __restrict__ fp_cols,
    const float* __restrict__ fp_vals, const int* __restrict__ rearange,
    const int* __restrict__ ordered, const float* __restrict__ dE,
    float* __restrict__ force) {
  int n = blockIdx.x * 256 + threadIdx.x;
  if (n >= NNZ_) return;
  int r = fp_rows[n];
  int src = ordered[rearange[r >> 7]];
  float contrib = fp_vals[n] * dE[(size_t)src * P_ + (r & 127)];
  atomicAdd(&force[fp_cols[n]], -contrib);
}

// ---------------- host ----------------
extern "C" void kernel_launch(void* const* d_in, const int* in_sizes, int n_in,
                              void* d_out, int out_size, void* d_ws, size_t ws_size,
                              hipStream_t stream) {
  const float *x[3], *w0[3], *b0[3], *w1[3], *b1[3], *w2[3], *b2[3];
  const int* idx[3];
  for (int e = 0; e < 3; e++) {
    const int o = e * 8;
    x[e]   = (const float*)d_in[o + 0];
    idx[e] = (const int*)  d_in[o + 1];
    w0[e]  = (const float*)d_in[o + 2];
    b0[e]  = (const float*)d_in[o + 3];
    w1[e]  = (const float*)d_in[o + 4];
    b1[e]  = (const float*)d_in[o + 5];
    w2[e]  = (const float*)d_in[o + 6];
    b2[e]  = (const float*)d_in[o + 7];
  }
  const int*   rearange = (const int*)  d_in[24];
  const int*   fp_rows  = (const int*)  d_in[25];
  const int*   fp_cols  = (const int*)  d_in[26];
  const float* fp_vals  = (const float*)d_in[27];
  float* out = (float*)d_out;   // [0,1000): energy, [1000,901000): force

  // adaptive chunk so 3 activation buffers + dE + sort scratch fit in ws
  size_t fixedBytes = ((size_t)Q_ * P_ + (size_t)NC_ * NIMG + 2048 + Q_) * 4;
  int chunk = 25000;
  while (chunk > 3125 && fixedBytes + (size_t)3 * chunk * H_ * 4 > ws_size) chunk >>= 1;

  float* h0  = (float*)d_ws;
  float* h1  = h0 + (size_t)chunk * H_;
  float* da0 = h1 + (size_t)chunk * H_;
  float* dE  = da0 + (size_t)chunk * H_;
  int* chunkHist = (int*)(dE + (size_t)Q_ * P_);
  int* binTotals = chunkHist + (size_t)NC_ * NIMG;
  int* binOffset = binTotals + 1024;
  int* ordered   = binOffset + 1024;

  hipMemsetAsync(d_out, 0, (size_t)out_size * sizeof(float), stream);

  const int nchunk = QE_ / chunk;
  for (int e = 0; e < 3; e++) {
    for (int c = 0; c < nchunk; c++) {
      const int base = c * chunk;
      dim3 g1((chunk + GTM - 1) / GTM, H_ / GTN);
      k_fc_fwd<<<g1, 256, 0, stream>>>(x[e] + (size_t)base * P_, w0[e], b0[e], h0, chunk, P_);
      k_fc_fwd<<<g1, 256, 0, stream>>>(h0, w1[e], b1[e], h1, chunk, H_);
      k_out<<<(chunk + 3) / 4, 256, 0, stream>>>(h1, w2[e], b2[e], idx[e] + base, out, chunk);
      k_bwd1<<<g1, 256, 0, stream>>>(h1, w2[e], w1[e], h0, da0, chunk);
      dim3 g2((chunk + GTM - 1) / GTM, P_ / GTN);
      k_bwd2<<<g2, 256, 0, stream>>>(da0, w0[e], dE, e * QE_ + base, chunk);
    }
  }

  k_hist<<<NC_, 256, 0, stream>>>(idx[0], idx[1], idx[2], chunkHist);
  k_scanchunks<<<NIMG, 256, 0, stream>>>(chunkHist, binTotals);
  k_binoffsets<<<1, 64, 0, stream>>>(binTotals, binOffset);
  k_scatter<<<NC_, 256, 0, stream>>>(idx[0], idx[1], idx[2], chunkHist, binOffset, ordered);
  k_force<<<(NNZ_ + 255) / 256, 256, 0, stream>>>(fp_rows, fp_cols, fp_vals, rearange,
                                                  ordered, dE, out + NIMG);
}

// Round 2
// 3384.649 us; speedup vs baseline: 2.6529x; 2.6529x over previous
//
#include <hip/hip_runtime.h>

#define P_   128
#define H_   512
#define QE_  100000
#define Q_   300000
#define NIMG 1000
#define NNZ_ 8000000
#define NC_  1172   // ceil(Q_/256)

typedef __attribute__((ext_vector_type(8))) short bf16x8;
typedef __attribute__((ext_vector_type(4))) float f32x4;

__device__ __forceinline__ ushort f2bf(float f) {
  union { float f; unsigned u; } v; v.f = f;
  unsigned r = v.u + 0x7FFF + ((v.u >> 16) & 1);   // RNE
  return (ushort)(r >> 16);
}
__device__ __forceinline__ float bf2f(ushort h) {
  union { unsigned u; float f; } v; v.u = ((unsigned)h) << 16;
  return v.f;
}

__device__ __forceinline__ void gload_lds16(const void* g, void* l) {
  __builtin_amdgcn_global_load_lds(
      (const __attribute__((address_space(1))) unsigned int*)g,
      (__attribute__((address_space(3))) unsigned int*)l, 16, 0, 0);
}

// ---- shared GEMM core: acc[4][4] += A[bm:bm+128, :K] @ Bt[bn:bn+128, :K]^T ----
// A row-major [M,lda] bf16; Bt row-major [N,ldb=K] bf16 (i.e. B transposed).
// 256 threads = 4 waves (2x2 of 64x64), 16x16x32 MFMA, 4x4 frags per wave.
__device__ __forceinline__ void gemm_core(
    const ushort* __restrict__ A, int lda,
    const ushort* __restrict__ Bt, int ldb,
    int M, int K, int bm, int bn,
    ushort* As, ushort* Bs, f32x4 acc[4][4]) {
  const int tid = threadIdx.x;
  const int lane = tid & 63;
  const int w = tid >> 6;
  const int wr = (w >> 1) * 64, wc = (w & 1) * 64;
  const int c8 = (tid & 3) * 8;        // k-offset of this thread's 8 elems
  const int rbase = tid >> 2;          // row 0..63 (round 0), +64 (round 1)
  const int fr = lane & 15, fk = (lane >> 4) * 8;

  for (int kt = 0; kt < K; kt += 32) {
#pragma unroll
    for (int r = 0; r < 2; ++r) {
      int row = r * 64 + rbase;
      if (bm + row < M)
        gload_lds16(A + (size_t)(bm + row) * lda + kt + c8, As + row * 32 + c8);
      gload_lds16(Bt + (size_t)(bn + row) * ldb + kt + c8, Bs + row * 32 + c8);
    }
    __syncthreads();   // drains vmcnt before any wave reads LDS
    bf16x8 af[4], bff[4];
#pragma unroll
    for (int i = 0; i < 4; ++i) {
      af[i]  = *(const bf16x8*)(As + (wr + i * 16 + fr) * 32 + fk);
      bff[i] = *(const bf16x8*)(Bs + (wc + i * 16 + fr) * 32 + fk);
    }
#pragma unroll
    for (int i = 0; i < 4; ++i)
#pragma unroll
      for (int j = 0; j < 4; ++j)
        acc[i][j] = __builtin_amdgcn_mfma_f32_16x16x32_bf16(af[i], bff[j], acc[i][j], 0, 0, 0);
    __syncthreads();   // protect LDS before next-tile overwrite
  }
}

// C/D layout: col = lane&15, row = (lane>>4)*4 + reg  [m89-verified]
#define EPILOGUE_LOOP(BODY)                                        \
  {                                                                \
    const int lane = threadIdx.x & 63;                             \
    const int w = threadIdx.x >> 6;                                \
    const int wr = (w >> 1) * 64, wc = (w & 1) * 64;               \
    _Pragma("unroll")                                              \
    for (int i = 0; i < 4; ++i) {                                  \
      _Pragma("unroll")                                            \
      for (int j = 0; j < 4; ++j) {                                \
        _Pragma("unroll")                                          \
        for (int r = 0; r < 4; ++r) {                              \
          int gm = bm + wr + i * 16 + (lane >> 4) * 4 + r;         \
          int gn = bn + wc + j * 16 + (lane & 15);                 \
          if (gm < M) { float v = acc[i][j][r]; BODY }             \
        }                                                          \
      }                                                            \
    }                                                              \
  }

// fwd FC: out = bf16(tanh(A @ W + b));  Bt = W^T as [N,K]
__global__ __launch_bounds__(256) void k_gemm_tanh(
    const ushort* __restrict__ A, int lda,
    const ushort* __restrict__ Bt, int ldb,
    const float* __restrict__ bias,
    ushort* __restrict__ out, int ldo, int M, int K) {
  __shared__ ushort As[128 * 32];
  __shared__ ushort Bs[128 * 32];
  const int bm = blockIdx.x * 128, bn = blockIdx.y * 128;
  f32x4 acc[4][4] = {};
  gemm_core(A, lda, Bt, ldb, M, K, bm, bn, As, Bs, acc);
  EPILOGUE_LOOP({ out[(size_t)gm * ldo + gn] = f2bf(tanhf(v + bias[gn])); })
}

// bwd layer-1: da0 = bf16( (da1 @ w1^T) * (1 - h0^2) );  Bt = w1 row-major
__global__ __launch_bounds__(256) void k_gemm_da0(
    const ushort* __restrict__ A, const ushort* __restrict__ Bt,
    const ushort* __restrict__ h0b, ushort* __restrict__ out, int M) {
  __shared__ ushort As[128 * 32];
  __shared__ ushort Bs[128 * 32];
  const int bm = blockIdx.x * 128, bn = blockIdx.y * 128;
  f32x4 acc[4][4] = {};
  gemm_core(A, H_, Bt, H_, M, H_, bm, bn, As, Bs, acc);
  EPILOGUE_LOOP({
    float h = bf2f(h0b[(size_t)gm * H_ + gn]);
    out[(size_t)gm * H_ + gn] = f2bf(v * (1.f - h * h));
  })
}

// bwd layer-0: dE[rowOff+m, 0:128] = da0 @ w0^T (fp32 out);  Bt = w0 row-major
__global__ __launch_bounds__(256) void k_gemm_dE(
    const ushort* __restrict__ A, const ushort* __restrict__ Bt,
    float* __restrict__ dE, int rowOff, int M) {
  __shared__ ushort As[128 * 32];
  __shared__ ushort Bs[128 * 32];
  const int bm = blockIdx.x * 128, bn = 0;
  f32x4 acc[4][4] = {};
  gemm_core(A, H_, Bt, H_, M, H_, bm, bn, As, Bs, acc);
  EPILOGUE_LOOP({ dE[(size_t)(rowOff + gm) * P_ + gn] = v; })
}

// fused: da1 = bf16(w2 * (1 - h1^2)) and energy[idx[row]] += h1 . w2 + b2
__global__ __launch_bounds__(256) void k_da1(
    const ushort* __restrict__ h1b, const float* __restrict__ w2,
    const float* __restrict__ b2, const int* __restrict__ idx,
    ushort* __restrict__ da1b, float* __restrict__ energy, int M) {
  const int w = threadIdx.x >> 6, lane = threadIdx.x & 63;
  const int row = blockIdx.x * 4 + w;
  if (row >= M) return;
  const ushort* hr = h1b + (size_t)row * H_;
  bf16x8 hv = *(const bf16x8*)(hr + lane * 8);
  float4 wa = *(const float4*)(w2 + lane * 8);
  float4 wb = *(const float4*)(w2 + lane * 8 + 4);
  float w2v[8] = {wa.x, wa.y, wa.z, wa.w, wb.x, wb.y, wb.z, wb.w};
  ushort ov[8];
  float e = 0.f;
#pragma unroll
  for (int j = 0; j < 8; ++j) {
    float h = bf2f((ushort)hv[j]);
    e += h * w2v[j];
    ov[j] = f2bf(w2v[j] * (1.f - h * h));
  }
  *(bf16x8*)(da1b + (size_t)row * H_ + lane * 8) = *(bf16x8*)ov;
#pragma unroll
  for (int off = 32; off; off >>= 1) e += __shfl_xor(e, off, 64);
  if (lane == 0) atomicAdd(&energy[idx[row]], e + b2[0]);
}

// ---------------- fp32 -> bf16 converts ----------------
__global__ __launch_bounds__(256) void k_cvt(const float* __restrict__ src,
                                             ushort* __restrict__ dst, int n) {
  int i = (blockIdx.x * 256 + threadIdx.x) * 4;
  if (i < n) {
    float4 v = *(const float4*)(src + i);
    ushort o[4] = {f2bf(v.x), f2bf(v.y), f2bf(v.z), f2bf(v.w)};
    *(uint2*)(dst + i) = *(uint2*)o;
  }
}

// dst[c*R + r] = bf16(src[r*C + c])   (dst is [C][R], coalesced writes)
__global__ __launch_bounds__(256) void k_cvt_t(const float* __restrict__ src,
                                               ushort* __restrict__ dst, int R, int C) {
  int i = blockIdx.x * 256 + threadIdx.x;
  if (i < R * C) {
    int c = i / R, r = i - c * R;
    dst[i] = f2bf(src[(size_t)r * C + c]);
  }
}

// ---------------- stable counting sort of 300k keys in [0,1000) ----------------
__device__ __forceinline__ int atom_key(int gi, const int* i0, const int* i1, const int* i2) {
  return gi < QE_ ? i0[gi] : (gi < 2 * QE_ ? i1[gi - QE_] : i2[gi - 2 * QE_]);
}

__global__ __launch_bounds__(256) void k_hist(
    const int* __restrict__ i0, const int* __restrict__ i1, const int* __restrict__ i2,
    int* __restrict__ chunkHist) {
  __shared__ int h[NIMG];
  for (int i = threadIdx.x; i < NIMG; i += 256) h[i] = 0;
  __syncthreads();
  int gi = blockIdx.x * 256 + threadIdx.x;
  if (gi < Q_) atomicAdd(&h[atom_key(gi, i0, i1, i2)], 1);
  __syncthreads();
  for (int i = threadIdx.x; i < NIMG; i += 256)
    chunkHist[(size_t)blockIdx.x * NIMG + i] = h[i];
}

__global__ __launch_bounds__(256) void k_scanchunks(int* __restrict__ chunkHist,
                                                    int* __restrict__ binTotals) {
  __shared__ int s[256];
  __shared__ int carry;
  const int b = blockIdx.x;
  if (threadIdx.x == 0) carry = 0;
  __syncthreads();
  for (int c0 = 0; c0 < NC_; c0 += 256) {
    int c = c0 + threadIdx.x;
    int v = (c < NC_) ? chunkHist[(size_t)c * NIMG + b] : 0;
    s[threadIdx.x] = v;
    __syncthreads();
#pragma unroll
    for (int off = 1; off < 256; off <<= 1) {
      int t = (threadIdx.x >= off) ? s[threadIdx.x - off] : 0;
      __syncthreads();
      s[threadIdx.x] += t;
      __syncthreads();
    }
    int incl = s[threadIdx.x];
    int base = carry;
    __syncthreads();
    if (c < NC_) chunkHist[(size_t)c * NIMG + b] = base + incl - v;
    if (threadIdx.x == 255) carry = base + s[255];
    __syncthreads();
  }
  if (threadIdx.x == 0) binTotals[b] = carry;
}

__global__ void k_binoffsets(const int* __restrict__ binTotals, int* __restrict__ binOffset) {
  if (threadIdx.x == 0 && blockIdx.x == 0) {
    int acc = 0;
    for (int b = 0; b < NIMG; b++) { binOffset[b] = acc; acc += binTotals[b]; }
  }
}

__global__ __launch_bounds__(256) void k_scatter(
    const int* __restrict__ i0, const int* __restrict__ i1, const int* __restrict__ i2,
    const int* __restrict__ chunkHist, const int* __restrict__ binOffset,
    int* __restrict__ ordered) {
  __shared__ int keys[256];
  int gi = blockIdx.x * 256 + threadIdx.x;
  int key = (gi < Q_) ? atom_key(gi, i0, i1, i2) : -1;
  keys[threadIdx.x] = key;
  __syncthreads();
  if (gi < Q_) {
    int rank = 0;
    for (int j = 0; j < threadIdx.x; j++) rank += (keys[j] == key) ? 1 : 0;
    ordered[binOffset[key] + chunkHist[(size_t)blockIdx.x * NIMG + key] + rank] = gi;
  }
}

// ---------------- force: 8M gathers + scatter-adds ----------------
__global__ __launch_bounds__(256) void k_force(
    const int* __restrict__ fp_rows, const int* __restrict__ fp_cols,
    const float* __restrict__ fp_vals, const int* __restrict__ rearange,
    const int* __restrict__ ordered, const float* __restrict__ dE,
    float* __restrict__ force) {
  int n = blockIdx.x * 256 + threadIdx.x;
  if (n >= NNZ_) return;
  int r = fp_rows[n];
  int src = ordered[rearange[r >> 7]];
  float contrib = fp_vals[n] * dE[(size_t)src * P_ + (r & 127)];
  atomicAdd(&force[fp_cols[n]], -contrib);
}

// ---------------- host ----------------
extern "C" void kernel_launch(void* const* d_in, const int* in_sizes, int n_in,
                              void* d_out, int out_size, void* d_ws, size_t ws_size,
                              hipStream_t stream) {
  const float *x[3], *w0[3], *b0[3], *w1[3], *b1[3], *w2[3], *b2[3];
  const int* idx[3];
  for (int e = 0; e < 3; e++) {
    const int o = e * 8;
    x[e]   = (const float*)d_in[o + 0];
    idx[e] = (const int*)  d_in[o + 1];
    w0[e]  = (const float*)d_in[o + 2];
    b0[e]  = (const float*)d_in[o + 3];
    w1[e]  = (const float*)d_in[o + 4];
    b1[e]  = (const float*)d_in[o + 5];
    w2[e]  = (const float*)d_in[o + 6];
    b2[e]  = (const float*)d_in[o + 7];
  }
  const int*   rearange = (const int*)  d_in[24];
  const int*   fp_rows  = (const int*)  d_in[25];
  const int*   fp_cols  = (const int*)  d_in[26];
  const float* fp_vals  = (const float*)d_in[27];
  float* out = (float*)d_out;   // [0,1000): energy, [1000,901000): force

  // fixed ws: dE + bf16 weights + sort scratch
  const size_t W_PER_E = 65536 + 65536 + 262144 + 262144;   // ushorts
  size_t fixedBytes = (size_t)Q_ * P_ * 4 + 3 * W_PER_E * 2 +
                      ((size_t)NC_ * NIMG + 2048 + Q_) * 4;
  int chunk = 50000;   // per-chunk bf16: x(128) + h0/h1/da1/da0(512 each) = 4352 B/row
  while (chunk > 3125 && fixedBytes + (size_t)chunk * 4352 > ws_size) chunk >>= 1;

  ushort* xb   = (ushort*)d_ws;
  ushort* h0b  = xb  + (size_t)chunk * P_;
  ushort* h1b  = h0b + (size_t)chunk * H_;
  ushort* da1b = h1b + (size_t)chunk * H_;
  ushort* da0b = da1b + (size_t)chunk * H_;
  float*  dE   = (float*)(da0b + (size_t)chunk * H_);
  ushort* wbase = (ushort*)(dE + (size_t)Q_ * P_);
  int* chunkHist = (int*)(wbase + 3 * W_PER_E);
  int* binTotals = chunkHist + (size_t)NC_ * NIMG;
  int* binOffset = binTotals + 1024;
  int* ordered   = binOffset + 1024;

  hipMemsetAsync(d_out, 0, (size_t)out_size * sizeof(float), stream);

  // convert weights (w0b | w0t | w1b | w1t per element)
  ushort *w0b[3], *w0t[3], *w1b[3], *w1t[3];
  for (int e = 0; e < 3; e++) {
    w0b[e] = wbase + e * W_PER_E;
    w0t[e] = w0b[e] + 65536;
    w1b[e] = w0t[e] + 65536;
    w1t[e] = w1b[e] + 262144;
    k_cvt<<<(65536 / 4 + 255) / 256, 256, 0, stream>>>(w0[e], w0b[e], 65536);
    k_cvt_t<<<(65536 + 255) / 256, 256, 0, stream>>>(w0[e], w0t[e], 128, 512);
    k_cvt<<<(262144 / 4 + 255) / 256, 256, 0, stream>>>(w1[e], w1b[e], 262144);
    k_cvt_t<<<(262144 + 255) / 256, 256, 0, stream>>>(w1[e], w1t[e], 512, 512);
  }

  const int nchunk = QE_ / chunk;
  for (int e = 0; e < 3; e++) {
    for (int c = 0; c < nchunk; c++) {
      const int base = c * chunk;
      const int M = chunk;
      dim3 gN((M + 127) / 128, H_ / 128);   // N=512
      dim3 gP((M + 127) / 128, 1);          // N=128
      k_cvt<<<((M * P_) / 4 + 255) / 256, 256, 0, stream>>>(
          x[e] + (size_t)base * P_, xb, M * P_);
      k_gemm_tanh<<<gN, 256, 0, stream>>>(xb, P_, w0t[e], P_, b0[e], h0b, H_, M, P_);
      k_gemm_tanh<<<gN, 256, 0, stream>>>(h0b, H_, w1t[e], H_, b1[e], h1b, H_, M, H_);
      k_da1<<<(M + 3) / 4, 256, 0, stream>>>(h1b, w2[e], b2[e], idx[e] + base,
                                             da1b, out, M);
      k_gemm_da0<<<gN, 256, 0, stream>>>(da1b, w1b[e], h0b, da0b, M);
      k_gemm_dE<<<gP, 256, 0, stream>>>(da0b, w0b[e], dE, e * QE_ + base, M);
    }
  }

  k_hist<<<NC_, 256, 0, stream>>>(idx[0], idx[1], idx[2], chunkHist);
  k_scanchunks<<<NIMG, 256, 0, stream>>>(chunkHist, binTotals);
  k_binoffsets<<<1, 64, 0, stream>>>(binTotals, binOffset);
  k_scatter<<<NC_, 256, 0, stream>>>(idx[0], idx[1], idx[2], chunkHist, binOffset, ordered);
  k_force<<<(NNZ_ + 255) / 256, 256, 0, stream>>>(fp_rows, fp_cols, fp_vals, rearange,
                                                  ordered, dE, out + NIMG);
}

// Round 3
// 2054.776 us; speedup vs baseline: 4.3698x; 1.6472x over previous
//
#include <hip/hip_runtime.h>

#define P_   128
#define H_   512
#define QE_  100000
#define Q_   300000
#define NIMG 1000
#define NNZ_ 8000000
#define NC_  1172   // ceil(Q_/256)
#define ROWS 64
#define NBLK 1563   // ceil(QE_/ROWS)

typedef __attribute__((ext_vector_type(8))) short bf16x8;
typedef __attribute__((ext_vector_type(4))) float f32x4;

__device__ __forceinline__ ushort f2bf(float f) {
  union { float f; unsigned u; } v; v.f = f;
  unsigned r = v.u + 0x7FFF + ((v.u >> 16) & 1);   // RNE
  return (ushort)(r >> 16);
}
__device__ __forceinline__ float bf2f(ushort h) {
  union { unsigned u; float f; } v; v.u = ((unsigned)h) << 16;
  return v.f;
}
__device__ __forceinline__ float fast_tanh(float x) {
  float e = __expf(2.f * x);          // large |x| -> +-1 exactly via inf/0
  return 1.f - 2.f / (e + 1.f);
}

struct ElemPtrs {
  const float* x; const int* idx;
  const ushort *w0t, *w0b, *w1t, *w1b;
  const float *b0, *b1, *w2, *b2;
};
struct AllPtrs { ElemPtrs e[3]; };

// ---- register-streamed-B GEMM phase: acc[i][j] += Alds[64xK] @ BtSlice[64xK]^T ----
// Alds: bf16 [64][K] with elem-index XOR swizzle ((row&7)<<3). BtSlice: global bf16
// row-major [64 cols of this wave][LDB], pre-offset. No barriers inside.
template <int K, int LDB>
__device__ __forceinline__ void gphase(const ushort* __restrict__ Alds,
                                       const ushort* __restrict__ Bt,
                                       int fr, int fk, f32x4 acc[4][4]) {
  const ushort* bp[4];
#pragma unroll
  for (int j = 0; j < 4; ++j) bp[j] = Bt + (size_t)(j * 16 + fr) * LDB + fk;
  const ushort* ap[4];
  int xr[4];
#pragma unroll
  for (int i = 0; i < 4; ++i) {
    int row = i * 16 + fr;
    ap[i] = Alds + row * K;
    xr[i] = (row & 7) << 3;
  }
  bf16x8 ac[4], bc[4];
#pragma unroll
  for (int i = 0; i < 4; ++i) ac[i] = *(const bf16x8*)(ap[i] + (fk ^ xr[i]));
#pragma unroll
  for (int j = 0; j < 4; ++j) bc[j] = *(const bf16x8*)(bp[j]);
#pragma unroll
  for (int kt = 0; kt < K; kt += 32) {
    bf16x8 an[4], bn[4];
    if (kt + 32 < K) {
#pragma unroll
      for (int j = 0; j < 4; ++j) bn[j] = *(const bf16x8*)(bp[j] + kt + 32);
#pragma unroll
      for (int i = 0; i < 4; ++i)
        an[i] = *(const bf16x8*)(ap[i] + (((kt + 32) + fk) ^ xr[i]));
    }
#pragma unroll
    for (int i = 0; i < 4; ++i)
#pragma unroll
      for (int j = 0; j < 4; ++j)
        acc[i][j] = __builtin_amdgcn_mfma_f32_16x16x32_bf16(ac[i], bc[j], acc[i][j], 0, 0, 0);
    if (kt + 32 < K) {
#pragma unroll
      for (int i = 0; i < 4; ++i) ac[i] = an[i];
#pragma unroll
      for (int j = 0; j < 4; ++j) bc[j] = bn[j];
    }
  }
}

// phase D variant: 16 rows x 64 cols per wave (acc[4])
template <int K, int LDB>
__device__ __forceinline__ void gphaseD(const ushort* __restrict__ Alds,
                                        const ushort* __restrict__ Bt,
                                        int rbase, int fr, int fk, f32x4 acc[4]) {
  const ushort* bp[4];
#pragma unroll
  for (int j = 0; j < 4; ++j) bp[j] = Bt + (size_t)(j * 16 + fr) * LDB + fk;
  const int row = rbase + fr;
  const ushort* ap = Alds + row * K;
  const int xr = (row & 7) << 3;
  bf16x8 ac = *(const bf16x8*)(ap + (fk ^ xr));
  bf16x8 bc[4];
#pragma unroll
  for (int j = 0; j < 4; ++j) bc[j] = *(const bf16x8*)(bp[j]);
#pragma unroll
  for (int kt = 0; kt < K; kt += 32) {
    bf16x8 an, bn[4];
    if (kt + 32 < K) {
#pragma unroll
      for (int j = 0; j < 4; ++j) bn[j] = *(const bf16x8*)(bp[j] + kt + 32);
      an = *(const bf16x8*)(ap + (((kt + 32) + fk) ^ xr));
    }
#pragma unroll
    for (int j = 0; j < 4; ++j)
      acc[j] = __builtin_amdgcn_mfma_f32_16x16x32_bf16(ac, bc[j], acc[j], 0, 0, 0);
    if (kt + 32 < K) {
      ac = an;
#pragma unroll
      for (int j = 0; j < 4; ++j) bc[j] = bn[j];
    }
  }
}

// ---------------- fused per-atom MLP fwd+bwd: 64 atoms / workgroup ----------------
__global__ __launch_bounds__(512) void k_fused(AllPtrs ps, ushort* __restrict__ dEb,
                                               float* __restrict__ energy) {
  __shared__ ushort bufA[ROWS * H_];   // h0
  __shared__ ushort bufB[ROWS * H_];   // da1, then da0(masked)
  __shared__ ushort bufX[ROWS * P_];   // x, then dE staging
  __shared__ float b0l[H_], b1l[H_], w2l[H_];
  __shared__ float e_lds[ROWS];

  const int bid = blockIdx.x;
  const int e = bid / NBLK;
  const int blk = bid - e * NBLK;
  const int base = blk * ROWS;
  const int Mloc = min(ROWS, QE_ - base);
  const ElemPtrs EP = ps.e[e];

  const int tid = threadIdx.x;
  const int w = tid >> 6;
  const int lane = tid & 63;
  const int fr = lane & 15;
  const int fk = (lane >> 4) * 8;
  const int q4 = (lane >> 4) * 4;

  // ---- preload: biases/w2 to LDS, e_lds=0, x fp32->bf16 swizzled into bufX ----
  b0l[tid] = EP.b0[tid];
  b1l[tid] = EP.b1[tid];
  w2l[tid] = EP.w2[tid];
  if (tid < ROWS) e_lds[tid] = 0.f;
#pragma unroll
  for (int s = 0; s < 2; ++s) {
    int q = tid * 2 + s;               // 0..1023 = 64 rows x 16 chunks(8 elems)
    int row = q >> 4, c = q & 15;
    ushort ov[8];
    if (row < Mloc) {
      const float* src = EP.x + (size_t)(base + row) * P_ + c * 8;
      float4 v0 = *(const float4*)src;
      float4 v1 = *(const float4*)(src + 4);
      ov[0] = f2bf(v0.x); ov[1] = f2bf(v0.y); ov[2] = f2bf(v0.z); ov[3] = f2bf(v0.w);
      ov[4] = f2bf(v1.x); ov[5] = f2bf(v1.y); ov[6] = f2bf(v1.z); ov[7] = f2bf(v1.w);
    } else {
#pragma unroll
      for (int t = 0; t < 8; ++t) ov[t] = 0;
    }
    int idx = (row * P_ + c * 8) ^ ((row & 7) << 3);
    *(bf16x8*)(bufX + idx) = *(bf16x8*)ov;
  }
  __syncthreads();

  // ---- phase A: h0 = tanh(x @ w0 + b0) -> bufA ----
  {
    f32x4 acc[4][4] = {};
    gphase<P_, P_>(bufX, EP.w0t + (size_t)(w * 64) * P_, fr, fk, acc);
#pragma unroll
    for (int j = 0; j < 4; ++j) {
      int col = w * 64 + j * 16 + fr;
      float bj = b0l[col];
#pragma unroll
      for (int i = 0; i < 4; ++i)
#pragma unroll
        for (int r = 0; r < 4; ++r) {
          int row = i * 16 + q4 + r;
          bufA[(row * H_ + col) ^ ((row & 7) << 3)] = f2bf(fast_tanh(acc[i][j][r] + bj));
        }
    }
  }
  __syncthreads();

  // ---- phase B: h1 = tanh(h0 @ w1 + b1); E += h1.w2; da1 = w2*(1-h1^2) -> bufB ----
  {
    f32x4 acc[4][4] = {};
    gphase<H_, H_>(bufA, EP.w1t + (size_t)(w * 64) * H_, fr, fk, acc);
    float ep[4][4] = {};
#pragma unroll
    for (int j = 0; j < 4; ++j) {
      int col = w * 64 + j * 16 + fr;
      float bj = b1l[col], wj = w2l[col];
#pragma unroll
      for (int i = 0; i < 4; ++i)
#pragma unroll
        for (int r = 0; r < 4; ++r) {
          int row = i * 16 + q4 + r;
          float h = fast_tanh(acc[i][j][r] + bj);
          ep[i][r] += h * wj;
          bufB[(row * H_ + col) ^ ((row & 7) << 3)] = f2bf(wj * (1.f - h * h));
        }
    }
#pragma unroll
    for (int i = 0; i < 4; ++i)
#pragma unroll
      for (int r = 0; r < 4; ++r) {
        float v = ep[i][r];
        v += __shfl_xor(v, 1, 64); v += __shfl_xor(v, 2, 64);
        v += __shfl_xor(v, 4, 64); v += __shfl_xor(v, 8, 64);
        if (fr == 0) atomicAdd(&e_lds[i * 16 + q4 + r], v);
      }
  }
  __syncthreads();
  if (tid < Mloc) atomicAdd(&energy[EP.idx[base + tid]], e_lds[tid] + EP.b2[0]);

  // ---- phase C: da0 = (da1 @ w1^T) * (1-h0^2) -> bufB (in-place after barrier) ----
  {
    f32x4 acc[4][4] = {};
    gphase<H_, H_>(bufB, EP.w1b + (size_t)(w * 64) * H_, fr, fk, acc);
    __syncthreads();   // all waves done reading da1 before overwrite
#pragma unroll
    for (int j = 0; j < 4; ++j) {
      int col = w * 64 + j * 16 + fr;
#pragma unroll
      for (int i = 0; i < 4; ++i)
#pragma unroll
        for (int r = 0; r < 4; ++r) {
          int row = i * 16 + q4 + r;
          int sidx = (row * H_ + col) ^ ((row & 7) << 3);
          float h = bf2f(bufA[sidx]);
          bufB[sidx] = f2bf(acc[i][j][r] * (1.f - h * h));
        }
    }
  }
  __syncthreads();

  // ---- phase D: dE = da0 @ w0^T -> bufX (linear) -> coalesced global bf16 ----
  {
    f32x4 acc4[4] = {};
    const int rbase = (w & 3) * 16;
    const int cbase = (w >> 2) * 64;
    gphaseD<H_, H_>(bufB, EP.w0b + (size_t)cbase * H_, rbase, fr, fk, acc4);
#pragma unroll
    for (int j = 0; j < 4; ++j) {
      int col = cbase + j * 16 + fr;
#pragma unroll
      for (int r = 0; r < 4; ++r)
        bufX[(rbase + q4 + r) * P_ + col] = f2bf(acc4[j][r]);
    }
  }
  __syncthreads();
  {
    const size_t rowOff = (size_t)e * QE_ + base;
#pragma unroll
    for (int s = 0; s < 2; ++s) {
      int q = tid * 2 + s;
      int row = q >> 4, c = q & 15;
      if (row < Mloc)
        *(bf16x8*)(dEb + (rowOff + row) * P_ + c * 8) = *(const bf16x8*)(bufX + q * 8);
    }
  }
}

// ---------------- fp32 -> bf16 weight converts ----------------
__global__ __launch_bounds__(256) void k_cvt(const float* __restrict__ src,
                                             ushort* __restrict__ dst, int n) {
  int i = (blockIdx.x * 256 + threadIdx.x) * 4;
  if (i < n) {
    float4 v = *(const float4*)(src + i);
    ushort o[4] = {f2bf(v.x), f2bf(v.y), f2bf(v.z), f2bf(v.w)};
    *(uint2*)(dst + i) = *(uint2*)o;
  }
}
__global__ __launch_bounds__(256) void k_cvt_t(const float* __restrict__ src,
                                               ushort* __restrict__ dst, int R, int C) {
  int i = blockIdx.x * 256 + threadIdx.x;
  if (i < R * C) {
    int c = i / R, r = i - c * R;
    dst[i] = f2bf(src[(size_t)r * C + c]);
  }
}

// ---------------- stable counting sort of 300k keys in [0,1000) ----------------
__device__ __forceinline__ int atom_key(int gi, const int* i0, const int* i1, const int* i2) {
  return gi < QE_ ? i0[gi] : (gi < 2 * QE_ ? i1[gi - QE_] : i2[gi - 2 * QE_]);
}

__global__ __launch_bounds__(256) void k_hist(
    const int* __restrict__ i0, const int* __restrict__ i1, const int* __restrict__ i2,
    int* __restrict__ chunkHist) {
  __shared__ int h[NIMG];
  for (int i = threadIdx.x; i < NIMG; i += 256) h[i] = 0;
  __syncthreads();
  int gi = blockIdx.x * 256 + threadIdx.x;
  if (gi < Q_) atomicAdd(&h[atom_key(gi, i0, i1, i2)], 1);
  __syncthreads();
  for (int i = threadIdx.x; i < NIMG; i += 256)
    chunkHist[(size_t)blockIdx.x * NIMG + i] = h[i];
}

__global__ __launch_bounds__(256) void k_scanchunks(int* __restrict__ chunkHist,
                                                    int* __restrict__ binTotals) {
  __shared__ int s[256];
  __shared__ int carry;
  const int b = blockIdx.x;
  if (threadIdx.x == 0) carry = 0;
  __syncthreads();
  for (int c0 = 0; c0 < NC_; c0 += 256) {
    int c = c0 + threadIdx.x;
    int v = (c < NC_) ? chunkHist[(size_t)c * NIMG + b] : 0;
    s[threadIdx.x] = v;
    __syncthreads();
#pragma unroll
    for (int off = 1; off < 256; off <<= 1) {
      int t = (threadIdx.x >= off) ? s[threadIdx.x - off] : 0;
      __syncthreads();
      s[threadIdx.x] += t;
      __syncthreads();
    }
    int incl = s[threadIdx.x];
    int base = carry;
    __syncthreads();
    if (c < NC_) chunkHist[(size_t)c * NIMG + b] = base + incl - v;
    if (threadIdx.x == 255) carry = base + s[255];
    __syncthreads();
  }
  if (threadIdx.x == 0) binTotals[b] = carry;
}

__global__ void k_binoffsets(const int* __restrict__ binTotals, int* __restrict__ binOffset) {
  if (threadIdx.x == 0 && blockIdx.x == 0) {
    int acc = 0;
    for (int b = 0; b < NIMG; b++) { binOffset[b] = acc; acc += binTotals[b]; }
  }
}

__global__ __launch_bounds__(256) void k_scatter(
    const int* __restrict__ i0, const int* __restrict__ i1, const int* __restrict__ i2,
    const int* __restrict__ chunkHist, const int* __restrict__ binOffset,
    int* __restrict__ ordered) {
  __shared__ int keys[256];
  int gi = blockIdx.x * 256 + threadIdx.x;
  int key = (gi < Q_) ? atom_key(gi, i0, i1, i2) : -1;
  keys[threadIdx.x] = key;
  __syncthreads();
  if (gi < Q_) {
    int rank = 0;
    for (int j = 0; j < threadIdx.x; j++) rank += (keys[j] == key) ? 1 : 0;
    ordered[binOffset[key] + chunkHist[(size_t)blockIdx.x * NIMG + key] + rank] = gi;
  }
}

// ---------------- force: 8M gathers (bf16 dE) + scatter-adds ----------------
__global__ __launch_bounds__(256) void k_force(
    const int* __restrict__ fp_rows, const int* __restrict__ fp_cols,
    const float* __restrict__ fp_vals, const int* __restrict__ rearange,
    const int* __restrict__ ordered, const ushort* __restrict__ dEb,
    float* __restrict__ force) {
  int n = blockIdx.x * 256 + threadIdx.x;
  if (n >= NNZ_) return;
  int r = fp_rows[n];
  int src = ordered[rearange[r >> 7]];
  float contrib = fp_vals[n] * bf2f(dEb[(size_t)src * P_ + (r & 127)]);
  atomicAdd(&force[fp_cols[n]], -contrib);
}

// ---------------- host ----------------
extern "C" void kernel_launch(void* const* d_in, const int* in_sizes, int n_in,
                              void* d_out, int out_size, void* d_ws, size_t ws_size,
                              hipStream_t stream) {
  const float *x[3], *w0[3], *b0[3], *w1[3], *b1[3], *w2[3], *b2[3];
  const int* idx[3];
  for (int e = 0; e < 3; e++) {
    const int o = e * 8;
    x[e]   = (const float*)d_in[o + 0];
    idx[e] = (const int*)  d_in[o + 1];
    w0[e]  = (const float*)d_in[o + 2];
    b0[e]  = (const float*)d_in[o + 3];
    w1[e]  = (const float*)d_in[o + 4];
    b1[e]  = (const float*)d_in[o + 5];
    w2[e]  = (const float*)d_in[o + 6];
    b2[e]  = (const float*)d_in[o + 7];
  }
  const int*   rearange = (const int*)  d_in[24];
  const int*   fp_rows  = (const int*)  d_in[25];
  const int*   fp_cols  = (const int*)  d_in[26];
  const float* fp_vals  = (const float*)d_in[27];
  float* out = (float*)d_out;   // [0,1000): energy, [1000,901000): force

  // ws: dEb (bf16 Q x 128) | bf16 weights | sort scratch   (~87 MB total)
  const size_t W_PER_E = 65536 + 65536 + 262144 + 262144;   // w0t|w0b|w1t|w1b ushorts
  ushort* dEb   = (ushort*)d_ws;
  ushort* wbase = dEb + (size_t)Q_ * P_;
  int* chunkHist = (int*)(wbase + 3 * W_PER_E);
  int* binTotals = chunkHist + (size_t)NC_ * NIMG;
  int* binOffset = binTotals + 1024;
  int* ordered   = binOffset + 1024;

  hipMemsetAsync(d_out, 0, (size_t)out_size * sizeof(float), stream);

  AllPtrs ps;
  for (int e = 0; e < 3; e++) {
    ushort* w0t = wbase + e * W_PER_E;
    ushort* w0b = w0t + 65536;
    ushort* w1t = w0b + 65536;
    ushort* w1b = w1t + 262144;
    k_cvt_t<<<(65536 + 255) / 256, 256, 0, stream>>>(w0[e], w0t, 128, 512);
    k_cvt<<<(65536 / 4 + 255) / 256, 256, 0, stream>>>(w0[e], w0b, 65536);
    k_cvt_t<<<(262144 + 255) / 256, 256, 0, stream>>>(w1[e], w1t, 512, 512);
    k_cvt<<<(262144 / 4 + 255) / 256, 256, 0, stream>>>(w1[e], w1b, 262144);
    ps.e[e] = ElemPtrs{x[e], idx[e], w0t, w0b, w1t, w1b, b0[e], b1[e], w2[e], b2[e]};
  }

  k_fused<<<3 * NBLK, 512, 0, stream>>>(ps, dEb, out);

  k_hist<<<NC_, 256, 0, stream>>>(idx[0], idx[1], idx[2], chunkHist);
  k_scanchunks<<<NIMG, 256, 0, stream>>>(chunkHist, binTotals);
  k_binoffsets<<<1, 64, 0, stream>>>(binTotals, binOffset);
  k_scatter<<<NC_, 256, 0, stream>>>(idx[0], idx[1], idx[2], chunkHist, binOffset, ordered);
  k_force<<<(NNZ_ + 255) / 256, 256, 0, stream>>>(fp_rows, fp_cols, fp_vals, rearange,
                                                  ordered, dEb, out + NIMG);
}

// Round 4
// 1958.704 us; speedup vs baseline: 4.5842x; 1.0490x over previous
//
#include <hip/hip_runtime.h>

#define P_   128
#define H_   512
#define QE_  100000
#define Q_   300000
#define NIMG 1000
#define NNZ_ 8000000
#define NC_  1172   // ceil(Q_/256)
#define ROWS 48
#define NBLK 2084   // ceil(QE_/ROWS)

typedef __attribute__((ext_vector_type(8))) short bf16x8;
typedef __attribute__((ext_vector_type(4))) float f32x4;

__device__ __forceinline__ ushort f2bf(float f) {
  union { float f; unsigned u; } v; v.f = f;
  unsigned r = v.u + 0x7FFF + ((v.u >> 16) & 1);   // RNE
  return (ushort)(r >> 16);
}
__device__ __forceinline__ float bf2f(ushort h) {
  union { unsigned u; float f; } v; v.u = ((unsigned)h) << 16;
  return v.f;
}
__device__ __forceinline__ float fast_tanh(float x) {
  float e = __expf(2.f * x);          // large |x| -> +-1 exactly via inf/0
  return 1.f - 2.f / (e + 1.f);
}

struct ElemPtrs {
  const float* x; const int* idx;
  const ushort *w0t, *w0b, *w1t, *w1b;
  const float *b0, *b1, *w2, *b2;
};
struct AllPtrs { ElemPtrs e[3]; };

// ---- reg-streamed-B GEMM phase: acc[MI][4] += Alds[48xK] @ B-cols^T ----
// Alds: bf16, row stride ASTR, elem-index XOR swizzle ((row&7)<<3).
// bp[j]: global bf16 pointer pre-offset to (col_j)*LDB + fk. No barriers.
template <int MI, int K, int ASTR>
__device__ __forceinline__ void gphase4(const ushort* __restrict__ Alds,
                                        const ushort* const* __restrict__ bp,
                                        int fr, int fk, f32x4 (*acc)[4]) {
  int xr[MI]; const ushort* ap[MI];
#pragma unroll
  for (int i = 0; i < MI; ++i) {
    int row = i * 16 + fr;
    ap[i] = Alds + row * ASTR;
    xr[i] = (row & 7) << 3;
  }
  bf16x8 bc[4];
#pragma unroll
  for (int j = 0; j < 4; ++j) bc[j] = *(const bf16x8*)(bp[j]);
#pragma unroll
  for (int kt = 0; kt < K; kt += 32) {
    bf16x8 bn[4];
    if (kt + 32 < K) {
#pragma unroll
      for (int j = 0; j < 4; ++j) bn[j] = *(const bf16x8*)(bp[j] + kt + 32);
    }
    bf16x8 ac[MI];
#pragma unroll
    for (int i = 0; i < MI; ++i)
      ac[i] = *(const bf16x8*)(ap[i] + ((kt + fk) ^ xr[i]));
#pragma unroll
    for (int i = 0; i < MI; ++i)
#pragma unroll
      for (int j = 0; j < 4; ++j)
        acc[i][j] = __builtin_amdgcn_mfma_f32_16x16x32_bf16(ac[i], bc[j], acc[i][j], 0, 0, 0);
    if (kt + 32 < K) {
#pragma unroll
      for (int j = 0; j < 4; ++j) bc[j] = bn[j];
    }
  }
}

// single-column-group variant (phase D): acc[MI]
template <int MI, int K, int ASTR>
__device__ __forceinline__ void gphase1(const ushort* __restrict__ Alds,
                                        const ushort* __restrict__ bp0,
                                        int fr, int fk, f32x4* acc) {
  int xr[MI]; const ushort* ap[MI];
#pragma unroll
  for (int i = 0; i < MI; ++i) {
    int row = i * 16 + fr;
    ap[i] = Alds + row * ASTR;
    xr[i] = (row & 7) << 3;
  }
  bf16x8 bc = *(const bf16x8*)(bp0);
#pragma unroll
  for (int kt = 0; kt < K; kt += 32) {
    bf16x8 bn;
    if (kt + 32 < K) bn = *(const bf16x8*)(bp0 + kt + 32);
    bf16x8 ac[MI];
#pragma unroll
    for (int i = 0; i < MI; ++i)
      ac[i] = *(const bf16x8*)(ap[i] + ((kt + fk) ^ xr[i]));
#pragma unroll
    for (int i = 0; i < MI; ++i)
      acc[i] = __builtin_amdgcn_mfma_f32_16x16x32_bf16(ac[i], bc, acc[i], 0, 0, 0);
    if (kt + 32 < K) bc = bn;
  }
}

// ---------------- fused per-atom MLP fwd+bwd: 48 atoms / workgroup ----------------
// LDS: buf 48x512 (h0 -> da0, in-place) + half 48x256 (x -> da1 strips -> dE stage)
__global__ __launch_bounds__(512, 4) void k_fused(AllPtrs ps, ushort* __restrict__ dEb,
                                                  float* __restrict__ energy) {
  __shared__ ushort buf[ROWS * H_];        // 49152 B
  __shared__ ushort half[ROWS * 256];      // 24576 B (x | da1 k-strips | dE stage)
  __shared__ float b0l[H_], b1l[H_], w2l[H_];
  __shared__ float e_lds[ROWS];

  const int bid = blockIdx.x;
  const int e = bid / NBLK;
  const int blk = bid - e * NBLK;
  const int base = blk * ROWS;
  const int Mloc = min(ROWS, QE_ - base);
  const ElemPtrs EP = ps.e[e];

  const int tid = threadIdx.x;
  const int w = tid >> 6;
  const int lane = tid & 63;
  const int fr = lane & 15;
  const int fk = (lane >> 4) * 8;
  const int q4 = (lane >> 4) * 4;

  // ---- preload: biases/w2 -> LDS, e_lds=0, x fp32->bf16 swizzled into half ----
  b0l[tid] = EP.b0[tid];
  b1l[tid] = EP.b1[tid];
  w2l[tid] = EP.w2[tid];
  if (tid < ROWS) e_lds[tid] = 0.f;
#pragma unroll
  for (int s = 0; s < 2; ++s) {
    int q = tid + s * 512;                  // 0..767 = 48 rows x 16 chunks(8 elems)
    if (q < ROWS * 16) {
      int row = q >> 4, c = q & 15;
      ushort ov[8];
      if (row < Mloc) {
        const float* src = EP.x + (size_t)(base + row) * P_ + c * 8;
        float4 v0 = *(const float4*)src;
        float4 v1 = *(const float4*)(src + 4);
        ov[0] = f2bf(v0.x); ov[1] = f2bf(v0.y); ov[2] = f2bf(v0.z); ov[3] = f2bf(v0.w);
        ov[4] = f2bf(v1.x); ov[5] = f2bf(v1.y); ov[6] = f2bf(v1.z); ov[7] = f2bf(v1.w);
      } else {
#pragma unroll
        for (int t = 0; t < 8; ++t) ov[t] = 0;
      }
      int idx = (row * P_ + c * 8) ^ ((row & 7) << 3);
      *(bf16x8*)(half + idx) = *(bf16x8*)ov;
    }
  }
  __syncthreads();

  // ---- phase A: h0 = tanh(x @ w0 + b0) -> buf ----
  {
    f32x4 acc[3][4] = {};
    const ushort* bp[4];
#pragma unroll
    for (int j = 0; j < 4; ++j)
      bp[j] = EP.w0t + (size_t)(w * 64 + j * 16 + fr) * P_ + fk;
    gphase4<3, P_, P_>(half, bp, fr, fk, acc);
#pragma unroll
    for (int j = 0; j < 4; ++j) {
      int col = w * 64 + j * 16 + fr;
      float bj = b0l[col];
#pragma unroll
      for (int i = 0; i < 3; ++i)
#pragma unroll
        for (int r = 0; r < 4; ++r) {
          int row = i * 16 + q4 + r;
          buf[(row * H_ + col) ^ ((row & 7) << 3)] = f2bf(fast_tanh(acc[i][j][r] + bj));
        }
    }
  }
  __syncthreads();   // h0 ready; x reads done (half reusable)

  // ---- phase B: h1 = tanh(h0 @ w1 + b1); E += h1.w2; da1 in two k-strips ----
  unsigned stash[3][2][2];   // strip-2 da1, bf16-packed
  {
    f32x4 acc[3][4] = {};
    const ushort* bp[4];
#pragma unroll
    for (int j = 0; j < 4; ++j) {
      int col = (j < 2) ? (w * 32 + j * 16 + fr) : (256 + w * 32 + (j - 2) * 16 + fr);
      bp[j] = EP.w1t + (size_t)col * H_ + fk;
    }
    gphase4<3, H_, H_>(buf, bp, fr, fk, acc);
    float ep[3][4] = {};
#pragma unroll
    for (int j = 0; j < 4; ++j) {
      int kidx = w * 32 + (j & 1) * 16 + fr;          // strip-local col (0..255)
      int col = (j < 2) ? kidx : (256 + kidx);
      float bj = b1l[col], wj = w2l[col];
      ushort dv[4];
#pragma unroll
      for (int i = 0; i < 3; ++i) {
#pragma unroll
        for (int r = 0; r < 4; ++r) {
          float h = fast_tanh(acc[i][j][r] + bj);
          ep[i][r] += h * wj;
          dv[r] = f2bf(wj * (1.f - h * h));
        }
        if (j < 2) {
#pragma unroll
          for (int r = 0; r < 4; ++r) {
            int row = i * 16 + q4 + r;
            half[(row * 256 + kidx) ^ ((row & 7) << 3)] = dv[r];
          }
        } else {
          stash[i][j - 2][0] = (unsigned)dv[0] | ((unsigned)dv[1] << 16);
          stash[i][j - 2][1] = (unsigned)dv[2] | ((unsigned)dv[3] << 16);
        }
      }
    }
#pragma unroll
    for (int i = 0; i < 3; ++i)
#pragma unroll
      for (int r = 0; r < 4; ++r) {
        float v = ep[i][r];
        v += __shfl_xor(v, 1, 64); v += __shfl_xor(v, 2, 64);
        v += __shfl_xor(v, 4, 64); v += __shfl_xor(v, 8, 64);
        if (fr == 0) atomicAdd(&e_lds[i * 16 + q4 + r], v);
      }
  }
  __syncthreads();   // strip1 + e_lds complete
  if (tid < Mloc) atomicAdd(&energy[EP.idx[base + tid]], e_lds[tid] + EP.b2[0]);

  // ---- phase C: da0 = (da1 @ w1^T) * (1-h0^2) -> buf (in-place over h0) ----
  {
    f32x4 acc[3][4] = {};
    const ushort* bp[4];
#pragma unroll
    for (int j = 0; j < 4; ++j)
      bp[j] = EP.w1b + (size_t)(w * 64 + j * 16 + fr) * H_ + fk;
    gphase4<3, 256, 256>(half, bp, fr, fk, acc);        // k = 0..255
    __syncthreads();   // part-1 reads done
#pragma unroll
    for (int i = 0; i < 3; ++i)
#pragma unroll
      for (int jj = 0; jj < 2; ++jj) {
        int kidx = w * 32 + jj * 16 + fr;
#pragma unroll
        for (int r = 0; r < 4; ++r) {
          int row = i * 16 + q4 + r;
          half[(row * 256 + kidx) ^ ((row & 7) << 3)] =
              (ushort)(stash[i][jj][r >> 1] >> ((r & 1) * 16));
        }
      }
    __syncthreads();   // strip2 ready
    const ushort* bp2[4];
#pragma unroll
    for (int j = 0; j < 4; ++j) bp2[j] = bp[j] + 256;
    gphase4<3, 256, 256>(half, bp2, fr, fk, acc);       // k = 256..511
#pragma unroll
    for (int j = 0; j < 4; ++j) {
      int col = w * 64 + j * 16 + fr;
#pragma unroll
      for (int i = 0; i < 3; ++i)
#pragma unroll
        for (int r = 0; r < 4; ++r) {
          int row = i * 16 + q4 + r;
          int sidx = (row * H_ + col) ^ ((row & 7) << 3);
          float m = bf2f(buf[sidx]);                    // h0 (only this lane's cell)
          buf[sidx] = f2bf(acc[i][j][r] * (1.f - m * m));
        }
    }
  }
  __syncthreads();   // da0 complete; da1 reads done

  // ---- phase D: dE = da0 @ w0^T -> half (linear stage) -> coalesced global ----
  {
    f32x4 acc[3] = {};
    const ushort* bp0 = EP.w0b + (size_t)(w * 16 + fr) * H_ + fk;
    gphase1<3, H_, H_>(buf, bp0, fr, fk, acc);
    int col = w * 16 + fr;
#pragma unroll
    for (int i = 0; i < 3; ++i)
#pragma unroll
      for (int r = 0; r < 4; ++r)
        half[(i * 16 + q4 + r) * P_ + col] = f2bf(acc[i][r]);
  }
  __syncthreads();
  {
    const size_t rowOff = (size_t)e * QE_ + base;
#pragma unroll
    for (int s = 0; s < 2; ++s) {
      int q = tid + s * 512;
      if (q < ROWS * 16) {
        int row = q >> 4, c = q & 15;
        if (row < Mloc)
          *(bf16x8*)(dEb + (rowOff + row) * P_ + c * 8) = *(const bf16x8*)(half + q * 8);
      }
    }
  }
}

// ---------------- fp32 -> bf16 weight converts ----------------
__global__ __launch_bounds__(256) void k_cvt(const float* __restrict__ src,
                                             ushort* __restrict__ dst, int n) {
  int i = (blockIdx.x * 256 + threadIdx.x) * 4;
  if (i < n) {
    float4 v = *(const float4*)(src + i);
    ushort o[4] = {f2bf(v.x), f2bf(v.y), f2bf(v.z), f2bf(v.w)};
    *(uint2*)(dst + i) = *(uint2*)o;
  }
}
__global__ __launch_bounds__(256) void k_cvt_t(const float* __restrict__ src,
                                               ushort* __restrict__ dst, int R, int C) {
  int i = blockIdx.x * 256 + threadIdx.x;
  if (i < R * C) {
    int c = i / R, r = i - c * R;
    dst[i] = f2bf(src[(size_t)r * C + c]);
  }
}

// ---------------- stable counting sort of 300k keys in [0,1000) ----------------
__device__ __forceinline__ int atom_key(int gi, const int* i0, const int* i1, const int* i2) {
  return gi < QE_ ? i0[gi] : (gi < 2 * QE_ ? i1[gi - QE_] : i2[gi - 2 * QE_]);
}

__global__ __launch_bounds__(256) void k_hist(
    const int* __restrict__ i0, const int* __restrict__ i1, const int* __restrict__ i2,
    int* __restrict__ chunkHist) {
  __shared__ int h[NIMG];
  for (int i = threadIdx.x; i < NIMG; i += 256) h[i] = 0;
  __syncthreads();
  int gi = blockIdx.x * 256 + threadIdx.x;
  if (gi < Q_) atomicAdd(&h[atom_key(gi, i0, i1, i2)], 1);
  __syncthreads();
  for (int i = threadIdx.x; i < NIMG; i += 256)
    chunkHist[(size_t)blockIdx.x * NIMG + i] = h[i];
}

__global__ __launch_bounds__(256) void k_scanchunks(int* __restrict__ chunkHist,
                                                    int* __restrict__ binTotals) {
  __shared__ int s[256];
  __shared__ int carry;
  const int b = blockIdx.x;
  if (threadIdx.x == 0) carry = 0;
  __syncthreads();
  for (int c0 = 0; c0 < NC_; c0 += 256) {
    int c = c0 + threadIdx.x;
    int v = (c < NC_) ? chunkHist[(size_t)c * NIMG + b] : 0;
    s[threadIdx.x] = v;
    __syncthreads();
#pragma unroll
    for (int off = 1; off < 256; off <<= 1) {
      int t = (threadIdx.x >= off) ? s[threadIdx.x - off] : 0;
      __syncthreads();
      s[threadIdx.x] += t;
      __syncthreads();
    }
    int incl = s[threadIdx.x];
    int base = carry;
    __syncthreads();
    if (c < NC_) chunkHist[(size_t)c * NIMG + b] = base + incl - v;
    if (threadIdx.x == 255) carry = base + s[255];
    __syncthreads();
  }
  if (threadIdx.x == 0) binTotals[b] = carry;
}

__global__ void k_binoffsets(const int* __restrict__ binTotals, int* __restrict__ binOffset) {
  if (threadIdx.x == 0 && blockIdx.x == 0) {
    int acc = 0;
    for (int b = 0; b < NIMG; b++) { binOffset[b] = acc; acc += binTotals[b]; }
  }
}

__global__ __launch_bounds__(256) void k_scatter(
    const int* __restrict__ i0, const int* __restrict__ i1, const int* __restrict__ i2,
    const int* __restrict__ chunkHist, const int* __restrict__ binOffset,
    int* __restrict__ ordered) {
  __shared__ int keys[256];
  int gi = blockIdx.x * 256 + threadIdx.x;
  int key = (gi < Q_) ? atom_key(gi, i0, i1, i2) : -1;
  keys[threadIdx.x] = key;
  __syncthreads();
  if (gi < Q_) {
    int rank = 0;
    for (int j = 0; j < threadIdx.x; j++) rank += (keys[j] == key) ? 1 : 0;
    ordered[binOffset[key] + chunkHist[(size_t)blockIdx.x * NIMG + key] + rank] = gi;
  }
}

// ---------------- force: 8M gathers (bf16 dE) + scatter-adds ----------------
__global__ __launch_bounds__(256) void k_force(
    const int* __restrict__ fp_rows, const int* __restrict__ fp_cols,
    const float* __restrict__ fp_vals, const int* __restrict__ rearange,
    const int* __restrict__ ordered, const ushort* __restrict__ dEb,
    float* __restrict__ force) {
  int n = blockIdx.x * 256 + threadIdx.x;
  if (n >= NNZ_) return;
  int r = fp_rows[n];
  int src = ordered[rearange[r >> 7]];
  float contrib = fp_vals[n] * bf2f(dEb[(size_t)src * P_ + (r & 127)]);
  atomicAdd(&force[fp_cols[n]], -contrib);
}

// ---------------- host ----------------
extern "C" void kernel_launch(void* const* d_in, const int* in_sizes, int n_in,
                              void* d_out, int out_size, void* d_ws, size_t ws_size,
                              hipStream_t stream) {
  const float *x[3], *w0[3], *b0[3], *w1[3], *b1[3], *w2[3], *b2[3];
  const int* idx[3];
  for (int e = 0; e < 3; e++) {
    const int o = e * 8;
    x[e]   = (const float*)d_in[o + 0];
    idx[e] = (const int*)  d_in[o + 1];
    w0[e]  = (const float*)d_in[o + 2];
    b0[e]  = (const float*)d_in[o + 3];
    w1[e]  = (const float*)d_in[o + 4];
    b1[e]  = (const float*)d_in[o + 5];
    w2[e]  = (const float*)d_in[o + 6];
    b2[e]  = (const float*)d_in[o + 7];
  }
  const int*   rearange = (const int*)  d_in[24];
  const int*   fp_rows  = (const int*)  d_in[25];
  const int*   fp_cols  = (const int*)  d_in[26];
  const float* fp_vals  = (const float*)d_in[27];
  float* out = (float*)d_out;   // [0,1000): energy, [1000,901000): force

  // ws: dEb (bf16 Q x 128) | bf16 weights | sort scratch   (~87 MB total)
  const size_t W_PER_E = 65536 + 65536 + 262144 + 262144;   // w0t|w0b|w1t|w1b ushorts
  ushort* dEb   = (ushort*)d_ws;
  ushort* wbase = dEb + (size_t)Q_ * P_;
  int* chunkHist = (int*)(wbase + 3 * W_PER_E);
  int* binTotals = chunkHist + (size_t)NC_ * NIMG;
  int* binOffset = binTotals + 1024;
  int* ordered   = binOffset + 1024;

  hipMemsetAsync(d_out, 0, (size_t)out_size * sizeof(float), stream);

  AllPtrs ps;
  for (int e = 0; e < 3; e++) {
    ushort* w0t = wbase + e * W_PER_E;
    ushort* w0b = w0t + 65536;
    ushort* w1t = w0b + 65536;
    ushort* w1b = w1t + 262144;
    k_cvt_t<<<(65536 + 255) / 256, 256, 0, stream>>>(w0[e], w0t, 128, 512);
    k_cvt<<<(65536 / 4 + 255) / 256, 256, 0, stream>>>(w0[e], w0b, 65536);
    k_cvt_t<<<(262144 + 255) / 256, 256, 0, stream>>>(w1[e], w1t, 512, 512);
    k_cvt<<<(262144 / 4 + 255) / 256, 256, 0, stream>>>(w1[e], w1b, 262144);
    ps.e[e] = ElemPtrs{x[e], idx[e], w0t, w0b, w1t, w1b, b0[e], b1[e], w2[e], b2[e]};
  }

  k_fused<<<3 * NBLK, 512, 0, stream>>>(ps, dEb, out);

  k_hist<<<NC_, 256, 0, stream>>>(idx[0], idx[1], idx[2], chunkHist);
  k_scanchunks<<<NIMG, 256, 0, stream>>>(chunkHist, binTotals);
  k_binoffsets<<<1, 64, 0, stream>>>(binTotals, binOffset);
  k_scatter<<<NC_, 256, 0, stream>>>(idx[0], idx[1], idx[2], chunkHist, binOffset, ordered);
  k_force<<<(NNZ_ + 255) / 256, 256, 0, stream>>>(fp_rows, fp_cols, fp_vals, rearange,
                                                  ordered, dEb, out + NIMG);
}